// Round 7
// baseline (380.926 us; speedup 1.0000x reference)
//
#include <hip/hip_runtime.h>
#include <hip/hip_bf16.h>
#include <math.h>

namespace {

constexpr int L   = 200;
constexpr int E   = 64;
constexpr int H1N = 80;
constexpr int H2N = 40;

using short8 = __attribute__((ext_vector_type(8))) short;
using f32x4  = __attribute__((ext_vector_type(4))) float;

__device__ inline short f2b(float f) {
    return __builtin_bit_cast(short, __float2bfloat16(f));   // HW RNE; compiler fuses pairs to v_cvt_pk_bf16_f32
}
__device__ inline unsigned short f2bu(float f) {
    return (unsigned short)__builtin_bit_cast(short, __float2bfloat16(f));
}
__device__ inline float b2f(unsigned short u) {
    union { unsigned uu; float f; } x; x.uu = ((unsigned)u) << 16; return x.f;
}

// DPP row_ror add: x += ror_n(x) within each 16-lane row (VALU pipe)
#define ROR_ADD(x, CTRL) do {                                                   \
    int _t = __builtin_amdgcn_update_dpp(0, __builtin_bit_cast(int, (x)),       \
                                         (CTRL), 0xf, 0xf, true);               \
    (x) += __builtin_bit_cast(float, _t); } while (0)

// ---- workspace layout (bytes) ----
constexpr int WS_ABF  = 0;        // bf16[1280*8] GEMM1 B-frags (K=128: A | C)
constexpr int WS_W2F  = 20480;    // bf16[576*8]  GEMM2 B-frags
constexpr int WS_FLAG = 29696;    // int: 1 if mask is int32, 0 if bytes
constexpr int WS_CQ   = 29952;    // f32 [B][80]  cq
// logits at WS_CQ + B*80*4:  f32 [B][200]  (or bf16 [B][200] fallback)

// ---- prep: frag packing + cq GEMV + mask-dtype sniff ----
__global__ void k0_prep(const float* __restrict__ W1,
                        const float* __restrict__ W2,
                        const float* __restrict__ q,
                        const float* __restrict__ b1,
                        const void* __restrict__ mask,
                        unsigned short* __restrict__ Abf,
                        unsigned short* __restrict__ W2f,
                        float* __restrict__ cq_all,
                        int* __restrict__ flagG, int B)
{
    const int id = blockIdx.x * 256 + threadIdx.x;
    if (id < 1280) {
        // frag u=(nt*4+ks)*64+lane; ks 0,1 -> A=(W1_k-W1_d); ks 2,3 -> C=W1_p
        const int u  = id, cc = u >> 6, ln = u & 63;
        const int nt = cc >> 2, ks = cc & 3;
        const int j  = nt * 16 + (ln & 15);
        const int i0 = (ks & 1) * 32 + (ln >> 4) * 8;
        #pragma unroll
        for (int e = 0; e < 8; ++e) {
            const int i = i0 + e;
            const float v = (ks < 2)
                ? (W1[(E + i) * H1N + j] - W1[(2 * E + i) * H1N + j])
                : W1[(3 * E + i) * H1N + j];
            Abf[u * 8 + e] = f2bu(v);
        }
    } else if (id < 1856) {
        const int u   = id - 1280, cc = u >> 6, ln = u & 63;
        const int nt2 = cc / 3, ks2 = cc % 3;
        const int n   = nt2 * 16 + (ln & 15);
        const int j0  = ks2 * 32 + (ln >> 4) * 8;
        #pragma unroll
        for (int e = 0; e < 8; ++e) {
            const int j = j0 + e;
            W2f[u * 8 + e] = (j < H1N && n < H2N) ? f2bu(W2[j * H2N + n])
                                                  : (unsigned short)0;
        }
    } else {
        const int t = id - 1856;
        if (t > B * 20) return;
        if (t == B * 20) {   // mask dtype sniff, once per launch
            const unsigned char* mb = (const unsigned char*)mask;
            int isI32 = 1;
            for (int i = 0; i < 256; ++i)
                if ((i & 3) && mb[i]) { isI32 = 0; break; }
            flagG[0] = isI32;
            return;
        }
        const int b  = t / 20;
        const int jq = (t - b * 20) * 4;
        const float* qb = q + (size_t)b * E;
        float4 a = *(const float4*)(b1 + jq);
        #pragma unroll 8
        for (int i = 0; i < E; ++i) {
            const float qv = qb[i];
            const float4 wa = *(const float4*)(W1 + i * H1N + jq);
            const float4 wb = *(const float4*)(W1 + (2 * E + i) * H1N + jq);
            a.x += qv * (wa.x + wb.x);
            a.y += qv * (wa.y + wb.y);
            a.z += qv * (wa.z + wb.z);
            a.w += qv * (wa.w + wb.w);
        }
        *(float4*)(cq_all + (size_t)b * H1N + jq) = a;
    }
}

// ---- kernel A: logits for every (b, 16-row tile); grid-stride, barrier-free ----
template<int LOGF32>
__global__ __launch_bounds__(256, 6)
void k_logits(const float* __restrict__ q,
              const float* __restrict__ kmat,
              const float* __restrict__ b2,
              const float* __restrict__ Wf,
              const float* __restrict__ bfp,
              const unsigned short* __restrict__ AbfG,
              const unsigned short* __restrict__ W2fG,
              const float* __restrict__ cq_all,
              void* __restrict__ logits, int B)
{
    const int tid  = threadIdx.x;
    const int lane = tid & 63;
    const int wv   = tid >> 6;
    const int g    = lane >> 4;
    const int c    = lane & 15;

    __shared__ unsigned short H1t[4][16][104];   // per-wave tiles, wave-local (no barrier)
    *(unsigned long long*)&H1t[wv][c][80 + g * 4] = 0ULL;   // K-pad cols 80..95

    float b2r[3], wfr[3];
    #pragma unroll
    for (int nt2 = 0; nt2 < 3; ++nt2) {
        const int nc = nt2 * 16 + c;
        b2r[nt2] = (nc < H2N) ? b2[nc] : 0.f;
        wfr[nt2] = (nc < H2N) ? Wf[nc] : 0.f;
    }
    const float bf0 = bfp[0];
    const short8* Ab  = (const short8*)AbfG;
    const short8* W2v = (const short8*)W2fG;

    const int NT = B * 13;
    const int stride = gridDim.x << 2;
    for (int T = blockIdx.x * 4 + wv; T < NT; T += stride) {
        const int b  = (int)((unsigned)T / 13u);
        const int tt = T - b * 13;
        const int row0 = tt * 16;

        // loads first (k from HBM is the long pole; q/cq are L2-hot)
        const float4* kp = (const float4*)(kmat + ((size_t)b * L + min(row0 + c, L - 1)) * E);
        const float4 kb0 = kp[2 * g];
        const float4 kb1 = kp[2 * g + 1];
        const float4 kb2 = kp[8 + 2 * g];
        const float4 kb3 = kp[8 + 2 * g + 1];
        const float4* qp = (const float4*)(q + (size_t)b * E);
        const float4 q0 = qp[2 * g];
        const float4 q1 = qp[2 * g + 1];
        const float4 q2 = qp[8 + 2 * g];
        const float4 q3 = qp[8 + 2 * g + 1];
        float cqr[5];
        #pragma unroll
        for (int nt = 0; nt < 5; ++nt)
            cqr[nt] = cq_all[(size_t)b * H1N + nt * 16 + c];

        short8 ak0, aq0, ak1, aq1;
        ak0[0] = f2b(kb0.x); ak0[1] = f2b(kb0.y); ak0[2] = f2b(kb0.z); ak0[3] = f2b(kb0.w);
        ak0[4] = f2b(kb1.x); ak0[5] = f2b(kb1.y); ak0[6] = f2b(kb1.z); ak0[7] = f2b(kb1.w);
        aq0[0] = f2b(kb0.x * q0.x); aq0[1] = f2b(kb0.y * q0.y);
        aq0[2] = f2b(kb0.z * q0.z); aq0[3] = f2b(kb0.w * q0.w);
        aq0[4] = f2b(kb1.x * q1.x); aq0[5] = f2b(kb1.y * q1.y);
        aq0[6] = f2b(kb1.z * q1.z); aq0[7] = f2b(kb1.w * q1.w);
        ak1[0] = f2b(kb2.x); ak1[1] = f2b(kb2.y); ak1[2] = f2b(kb2.z); ak1[3] = f2b(kb2.w);
        ak1[4] = f2b(kb3.x); ak1[5] = f2b(kb3.y); ak1[6] = f2b(kb3.z); ak1[7] = f2b(kb3.w);
        aq1[0] = f2b(kb2.x * q2.x); aq1[1] = f2b(kb2.y * q2.y);
        aq1[2] = f2b(kb2.z * q2.z); aq1[3] = f2b(kb2.w * q2.w);
        aq1[4] = f2b(kb3.x * q3.x); aq1[5] = f2b(kb3.y * q3.y);
        aq1[6] = f2b(kb3.z * q3.z); aq1[7] = f2b(kb3.w * q3.w);

        f32x4 acc1[5];
        #pragma unroll
        for (int nt = 0; nt < 5; ++nt) acc1[nt] = f32x4{0.f, 0.f, 0.f, 0.f};
        #pragma unroll
        for (int nt = 0; nt < 5; ++nt) {
            acc1[nt] = __builtin_amdgcn_mfma_f32_16x16x32_bf16(ak0, Ab[(nt * 4 + 0) * 64 + lane], acc1[nt], 0, 0, 0);
            acc1[nt] = __builtin_amdgcn_mfma_f32_16x16x32_bf16(aq0, Ab[(nt * 4 + 2) * 64 + lane], acc1[nt], 0, 0, 0);
            acc1[nt] = __builtin_amdgcn_mfma_f32_16x16x32_bf16(ak1, Ab[(nt * 4 + 1) * 64 + lane], acc1[nt], 0, 0, 0);
            acc1[nt] = __builtin_amdgcn_mfma_f32_16x16x32_bf16(aq1, Ab[(nt * 4 + 3) * 64 + lane], acc1[nt], 0, 0, 0);
        }

        #pragma unroll
        for (int nt = 0; nt < 5; ++nt)
            #pragma unroll
            for (int r = 0; r < 4; ++r)
                H1t[wv][4 * g + r][nt * 16 + c] = f2bu(acc1[nt][r] + cqr[nt]);

        f32x4 acc2[3];
        #pragma unroll
        for (int nt2 = 0; nt2 < 3; ++nt2) acc2[nt2] = f32x4{0.f, 0.f, 0.f, 0.f};
        #pragma unroll
        for (int ks2 = 0; ks2 < 3; ++ks2) {
            const short8 a2 = *(const short8*)&H1t[wv][c][ks2 * 32 + g * 8];
            #pragma unroll
            for (int nt2 = 0; nt2 < 3; ++nt2)
                acc2[nt2] = __builtin_amdgcn_mfma_f32_16x16x32_bf16(a2, W2v[(nt2 * 3 + ks2) * 64 + lane], acc2[nt2], 0, 0, 0);
        }

        float pl0 = 0.f, pl1 = 0.f, pl2 = 0.f, pl3 = 0.f;
        #pragma unroll
        for (int nt2 = 0; nt2 < 3; ++nt2) {
            const float wfv = wfr[nt2], b2v = b2r[nt2];
            pl0 += wfv * __builtin_amdgcn_rcpf(1.f + __expf(-(acc2[nt2][0] + b2v)));
            pl1 += wfv * __builtin_amdgcn_rcpf(1.f + __expf(-(acc2[nt2][1] + b2v)));
            pl2 += wfv * __builtin_amdgcn_rcpf(1.f + __expf(-(acc2[nt2][2] + b2v)));
            pl3 += wfv * __builtin_amdgcn_rcpf(1.f + __expf(-(acc2[nt2][3] + b2v)));
        }
        ROR_ADD(pl0, 0x128); ROR_ADD(pl0, 0x124); ROR_ADD(pl0, 0x122); ROR_ADD(pl0, 0x121);
        ROR_ADD(pl1, 0x128); ROR_ADD(pl1, 0x124); ROR_ADD(pl1, 0x122); ROR_ADD(pl1, 0x121);
        ROR_ADD(pl2, 0x128); ROR_ADD(pl2, 0x124); ROR_ADD(pl2, 0x122); ROR_ADD(pl2, 0x121);
        ROR_ADD(pl3, 0x128); ROR_ADD(pl3, 0x124); ROR_ADD(pl3, 0x122); ROR_ADD(pl3, 0x121);
        const float myv = (c == 0) ? pl0 : (c == 1) ? pl1 : (c == 2) ? pl2 : pl3;
        const int rowi = row0 + 4 * g + c;
        if (c < 4 && rowi < L) {
            const float lg = bf0 + myv;
            if (LOGF32) ((float*)logits)[(size_t)b * L + rowi] = lg;
            else        ((unsigned short*)logits)[(size_t)b * L + rowi] = f2bu(lg);
        }
    }
}

// ---- kernel B: masked softmax + PV, wave-per-batch, barrier-free ----
template<int LOGF32>
__global__ __launch_bounds__(256, 8)
void k_pv(const void* __restrict__ logits,
          const void* __restrict__ mask,
          const float* __restrict__ vmat,
          const int* __restrict__ flagG,
          float* __restrict__ out, int B)
{
    const int tid  = threadIdx.x;
    const int lane = tid & 63;
    const int wv   = tid >> 6;
    const int g    = lane >> 4;
    const int c    = lane & 15;

    __shared__ float sc[4][200];

    const int bb = blockIdx.x * 4 + wv;
    if (bb >= B) return;   // no barriers anywhere

    float lg0 = -INFINITY, lg1 = -INFINITY, lg2 = -INFINITY, lg3 = -INFINITY;
    if (lane < 50) {
        if (LOGF32) {
            const float4 t = ((const float4*)logits)[bb * 50 + lane];
            lg0 = t.x; lg1 = t.y; lg2 = t.z; lg3 = t.w;
        } else {
            const ushort4 t = ((const ushort4*)logits)[bb * 50 + lane];
            lg0 = b2f(t.x); lg1 = b2f(t.y); lg2 = b2f(t.z); lg3 = b2f(t.w);
        }
        if (flagG[0]) {
            const int4 m4 = *(const int4*)((const int*)mask + (size_t)bb * L + lane * 4);
            if (m4.x) lg0 = -INFINITY;
            if (m4.y) lg1 = -INFINITY;
            if (m4.z) lg2 = -INFINITY;
            if (m4.w) lg3 = -INFINITY;
        } else {
            const unsigned mb = *(const unsigned*)((const unsigned char*)mask + (size_t)bb * L + lane * 4);
            if (mb & 0x000000ffu) lg0 = -INFINITY;
            if (mb & 0x0000ff00u) lg1 = -INFINITY;
            if (mb & 0x00ff0000u) lg2 = -INFINITY;
            if (mb & 0xff000000u) lg3 = -INFINITY;
        }
    }
    float mx = fmaxf(fmaxf(lg0, lg1), fmaxf(lg2, lg3));
    #pragma unroll
    for (int off = 32; off > 0; off >>= 1)
        mx = fmaxf(mx, __shfl_xor(mx, off));
    const float e0 = __expf(lg0 - mx), e1 = __expf(lg1 - mx);
    const float e2 = __expf(lg2 - mx), e3 = __expf(lg3 - mx);
    float es = (e0 + e1) + (e2 + e3);
    #pragma unroll
    for (int off = 32; off > 0; off >>= 1)
        es += __shfl_xor(es, off);
    const float inv = 1.0f / es;
    if (lane < 50)
        *(float4*)&sc[wv][lane * 4] = make_float4(e0 * inv, e1 * inv, e2 * inv, e3 * inv);
    // wave-local LDS: compiler inserts lgkmcnt; no __syncthreads needed (single-wave producer/consumer)

    f32x4 oa = f32x4{0.f, 0.f, 0.f, 0.f};
    const float* vb = vmat + (size_t)bb * (L * E);
    #pragma unroll 10
    for (int ll = 0; ll < 50; ++ll) {
        const int row = 4 * ll + g;
        const float sv = sc[wv][row];
        const float4 v4 = *(const float4*)(vb + row * E + c * 4);
        oa[0] += sv * v4.x; oa[1] += sv * v4.y;
        oa[2] += sv * v4.z; oa[3] += sv * v4.w;
    }
    #pragma unroll
    for (int j = 0; j < 4; ++j) {
        oa[j] += __shfl_xor(oa[j], 16);
        oa[j] += __shfl_xor(oa[j], 32);
    }
    if (g == 0) {
        float4 o;
        o.x = oa[0]; o.y = oa[1]; o.z = oa[2]; o.w = oa[3];
        *(float4*)(out + (size_t)bb * E + c * 4) = o;
    }
}

} // namespace

extern "C" void kernel_launch(void* const* d_in, const int* in_sizes, int n_in,
                              void* d_out, int out_size, void* d_ws, size_t ws_size,
                              hipStream_t stream) {
    const float* q  = (const float*)d_in[0];
    const float* k  = (const float*)d_in[1];
    const float* v  = (const float*)d_in[2];
    const void*  mk = d_in[3];
    const float* W1 = (const float*)d_in[4];
    const float* b1 = (const float*)d_in[5];
    const float* W2 = (const float*)d_in[6];
    const float* b2 = (const float*)d_in[7];
    const float* Wf = (const float*)d_in[8];
    const float* bf = (const float*)d_in[9];
    float* out = (float*)d_out;

    const int B = in_sizes[0] / E;   // 4096

    char* ws = (char*)d_ws;
    unsigned short* Abf    = (unsigned short*)(ws + WS_ABF);
    unsigned short* W2f    = (unsigned short*)(ws + WS_W2F);
    int*            flagG  = (int*)(ws + WS_FLAG);
    float*          cq_all = (float*)(ws + WS_CQ);
    const size_t log_off   = (size_t)WS_CQ + (size_t)B * H1N * 4;
    void*           logits = (void*)(ws + log_off);
    const bool lf32 = (ws_size == 0) || (ws_size >= log_off + (size_t)B * L * 4);

    const int prep_ids = 1856 + B * 20 + 1;
    k0_prep<<<(prep_ids + 255) / 256, 256, 0, stream>>>(W1, W2, q, b1, mk,
                                                        Abf, W2f, cq_all, flagG, B);
    if (lf32) {
        k_logits<1><<<2048, 256, 0, stream>>>(q, k, b2, Wf, bf, Abf, W2f, cq_all, logits, B);
        k_pv<1><<<(B + 3) / 4, 256, 0, stream>>>(logits, mk, v, flagG, out, B);
    } else {
        k_logits<0><<<2048, 256, 0, stream>>>(q, k, b2, Wf, bf, Abf, W2f, cq_all, logits, B);
        k_pv<0><<<(B + 3) / 4, 256, 0, stream>>>(logits, mk, v, flagG, out, B);
    }
}

// Round 9
// 123.977 us; speedup vs baseline: 3.0725x; 3.0725x over previous
//
#include <hip/hip_runtime.h>
#include <hip/hip_bf16.h>
#include <math.h>

namespace {

constexpr int L   = 200;
constexpr int E   = 64;
constexpr int H1N = 80;
constexpr int H2N = 40;

using short8 = __attribute__((ext_vector_type(8))) short;
using f32x4  = __attribute__((ext_vector_type(4))) float;

__device__ inline unsigned short f2bu(float f) {
    return (unsigned short)__builtin_bit_cast(short, __float2bfloat16(f));   // HW RNE
}

// DPP row_ror add: x += ror_n(x) within each 16-lane row (VALU pipe)
#define ROR_ADD(x, CTRL) do {                                                   \
    int _t = __builtin_amdgcn_update_dpp(0, __builtin_bit_cast(int, (x)),       \
                                         (CTRL), 0xf, 0xf, true);               \
    (x) += __builtin_bit_cast(float, _t); } while (0)

// ---- workspace layout (bytes) ----
constexpr int WS_AF   = 0;        // f32[640*8]  A=(W1_k-W1_d), GEMM1 frag order (K=64)
constexpr int WS_CF   = 20480;    // f32[640*8]  C=W1_p,        GEMM1 frag order
constexpr int WS_W2F  = 40960;    // bf16[576*8] GEMM2 B-frags
constexpr int WS_FLAG = 50176;    // int: 1 if mask is int32, 0 if bytes
constexpr int WS_CQ   = 50432;    // f32 [B][80] cq

// ---- prep: frag packing + cq GEMV + mask-dtype sniff ----
__global__ void k0_prep(const float* __restrict__ W1,
                        const float* __restrict__ W2,
                        const float* __restrict__ q,
                        const float* __restrict__ b1,
                        const void* __restrict__ mask,
                        float* __restrict__ Af,
                        float* __restrict__ Cf,
                        unsigned short* __restrict__ W2f,
                        float* __restrict__ cq_all,
                        int* __restrict__ flagG, int B)
{
    const int id = blockIdx.x * 256 + threadIdx.x;
    if (id < 640) {
        // GEMM1 frag u=(nt*2+ks)*64+lane; lane=16g+c: j=nt*16+c, i0=ks*32+g*8
        const int u  = id, cc = u >> 6, ln = u & 63;
        const int nt = cc >> 1, ks = cc & 1;
        const int j  = nt * 16 + (ln & 15);
        const int i0 = ks * 32 + (ln >> 4) * 8;
        #pragma unroll
        for (int e = 0; e < 8; ++e) {
            const int i = i0 + e;
            Af[u * 8 + e] = W1[(E + i) * H1N + j] - W1[(2 * E + i) * H1N + j];
            Cf[u * 8 + e] = W1[(3 * E + i) * H1N + j];
        }
    } else if (id < 1216) {
        const int u   = id - 640, cc = u >> 6, ln = u & 63;
        const int nt2 = cc / 3, ks2 = cc % 3;
        const int n   = nt2 * 16 + (ln & 15);
        const int j0  = ks2 * 32 + (ln >> 4) * 8;
        #pragma unroll
        for (int e = 0; e < 8; ++e) {
            const int j = j0 + e;
            W2f[u * 8 + e] = (j < H1N && n < H2N) ? f2bu(W2[j * H2N + n])
                                                  : (unsigned short)0;
        }
    } else {
        const int t = id - 1216;
        if (t > B * 20) return;
        if (t == B * 20) {   // mask dtype sniff, once per launch
            const unsigned char* mb = (const unsigned char*)mask;
            int isI32 = 1;
            for (int i = 0; i < 256; ++i)
                if ((i & 3) && mb[i]) { isI32 = 0; break; }
            flagG[0] = isI32;
            return;
        }
        const int b  = t / 20;
        const int jq = (t - b * 20) * 4;
        const float* qb = q + (size_t)b * E;
        float4 a = *(const float4*)(b1 + jq);
        #pragma unroll 8
        for (int i = 0; i < E; ++i) {
            const float qv = qb[i];
            const float4 wa = *(const float4*)(W1 + i * H1N + jq);
            const float4 wb = *(const float4*)(W1 + (2 * E + i) * H1N + jq);
            a.x += qv * (wa.x + wb.x);
            a.y += qv * (wa.y + wb.y);
            a.z += qv * (wa.z + wb.z);
            a.w += qv * (wa.w + wb.w);
        }
        *(float4*)(cq_all + (size_t)b * H1N + jq) = a;
    }
}

__global__ __launch_bounds__(256, 6)
void attn_main(const float* __restrict__ q,
               const float* __restrict__ kmat,
               const float* __restrict__ vmat,
               const void* __restrict__ mask,
               const float* __restrict__ b2,
               const float* __restrict__ Wf,
               const float* __restrict__ bfp,
               const float* __restrict__ Af,
               const float* __restrict__ Cf,
               const unsigned short* __restrict__ W2fG,
               const float* __restrict__ cq_all,
               const int* __restrict__ flagG,
               float* __restrict__ out)
{
    const int tid  = threadIdx.x;
    const int lane = tid & 63;
    const int wv   = tid >> 6;
    const int g    = lane >> 4;
    const int c    = lane & 15;

    __shared__ short8 Mt[640];                   // 10240 B: folded GEMM1 B-frags (K=64)
    __shared__ unsigned short H1t[4][16][104];   // 13312 B: per-wave H1 tiles
    __shared__ float score[256];                 //  1024 B
    __shared__ float part_s[4][64];              //  1024 B
    __shared__ float red_s[8];

    const int bb = blockIdx.x;                   // one batch per block

    // per-wave H1t K-pad zero (cols 80..95)
    *(unsigned long long*)&H1t[wv][c][80 + g * 4] = 0ULL;

    // ---- fold Mtf = bf16(A + q*C) into LDS (f32 math, frag order; R3 numerics) ----
    const float* qbase = q + (size_t)bb * E;
    for (int u = tid; u < 640; u += 256) {
        const int cc = u >> 6, ln = u & 63;
        const int i0 = (cc & 1) * 32 + (ln >> 4) * 8;
        const float4 a0 = *(const float4*)(Af + u * 8);
        const float4 a1 = *(const float4*)(Af + u * 8 + 4);
        const float4 c0 = *(const float4*)(Cf + u * 8);
        const float4 c1 = *(const float4*)(Cf + u * 8 + 4);
        const float4 q0 = *(const float4*)(qbase + i0);
        const float4 q1 = *(const float4*)(qbase + i0 + 4);
        short8 h;
        h[0] = (short)f2bu(a0.x + q0.x * c0.x);
        h[1] = (short)f2bu(a0.y + q0.y * c0.y);
        h[2] = (short)f2bu(a0.z + q0.z * c0.z);
        h[3] = (short)f2bu(a0.w + q0.w * c0.w);
        h[4] = (short)f2bu(a1.x + q1.x * c1.x);
        h[5] = (short)f2bu(a1.y + q1.y * c1.y);
        h[6] = (short)f2bu(a1.z + q1.z * c1.z);
        h[7] = (short)f2bu(a1.w + q1.w * c1.w);
        Mt[u] = h;
    }

    // ---- per-batch setup (overlaps fold; no LDS dependence) ----
    float cqr[5];
    #pragma unroll
    for (int nt = 0; nt < 5; ++nt)
        cqr[nt] = cq_all[(size_t)bb * H1N + nt * 16 + c];
    float b2r[3], wfr[3];
    #pragma unroll
    for (int nt2 = 0; nt2 < 3; ++nt2) {
        const int nc = nt2 * 16 + c;
        b2r[nt2] = (nc < H2N) ? b2[nc] : 0.f;
        wfr[nt2] = (nc < H2N) ? Wf[nc] : 0.f;
    }
    const float bf0 = bfp[0];
    const short8* W2v = (const short8*)W2fG;     // 9.2 KB, L1-resident
    const float*  kbase = kmat + (size_t)bb * (L * E);
    __syncthreads();

    // ---- 13 tiles of 16 rows split across 4 waves ----
    #pragma unroll 1
    for (int rt = 0; rt < 4; ++rt) {
        const int t = wv + 4 * rt;
        if (t < 13) {
            const float4* kp = (const float4*)(kbase + (size_t)min(16 * t + c, L - 1) * E);
            const float4 kb0 = kp[2 * g];
            const float4 kb1 = kp[2 * g + 1];
            const float4 kb2 = kp[8 + 2 * g];
            const float4 kb3 = kp[8 + 2 * g + 1];

            short8 ak0, ak1;
            ak0[0] = (short)f2bu(kb0.x); ak0[1] = (short)f2bu(kb0.y);
            ak0[2] = (short)f2bu(kb0.z); ak0[3] = (short)f2bu(kb0.w);
            ak0[4] = (short)f2bu(kb1.x); ak0[5] = (short)f2bu(kb1.y);
            ak0[6] = (short)f2bu(kb1.z); ak0[7] = (short)f2bu(kb1.w);
            ak1[0] = (short)f2bu(kb2.x); ak1[1] = (short)f2bu(kb2.y);
            ak1[2] = (short)f2bu(kb2.z); ak1[3] = (short)f2bu(kb2.w);
            ak1[4] = (short)f2bu(kb3.x); ak1[5] = (short)f2bu(kb3.y);
            ak1[6] = (short)f2bu(kb3.z); ak1[7] = (short)f2bu(kb3.w);

            f32x4 acc1[5];
            #pragma unroll
            for (int nt = 0; nt < 5; ++nt) acc1[nt] = f32x4{0.f, 0.f, 0.f, 0.f};
            #pragma unroll
            for (int nt = 0; nt < 5; ++nt) {
                acc1[nt] = __builtin_amdgcn_mfma_f32_16x16x32_bf16(ak0, Mt[(nt * 2 + 0) * 64 + lane], acc1[nt], 0, 0, 0);
                acc1[nt] = __builtin_amdgcn_mfma_f32_16x16x32_bf16(ak1, Mt[(nt * 2 + 1) * 64 + lane], acc1[nt], 0, 0, 0);
            }

            #pragma unroll
            for (int nt = 0; nt < 5; ++nt)
                #pragma unroll
                for (int r = 0; r < 4; ++r)
                    H1t[wv][4 * g + r][nt * 16 + c] = f2bu(acc1[nt][r] + cqr[nt]);

            f32x4 acc2[3];
            #pragma unroll
            for (int nt2 = 0; nt2 < 3; ++nt2) acc2[nt2] = f32x4{0.f, 0.f, 0.f, 0.f};
            #pragma unroll
            for (int ks2 = 0; ks2 < 3; ++ks2) {
                const short8 a2 = *(const short8*)&H1t[wv][c][ks2 * 32 + g * 8];
                #pragma unroll
                for (int nt2 = 0; nt2 < 3; ++nt2)
                    acc2[nt2] = __builtin_amdgcn_mfma_f32_16x16x32_bf16(a2, W2v[(nt2 * 3 + ks2) * 64 + lane], acc2[nt2], 0, 0, 0);
            }

            float pl0 = 0.f, pl1 = 0.f, pl2 = 0.f, pl3 = 0.f;
            #pragma unroll
            for (int nt2 = 0; nt2 < 3; ++nt2) {
                const float wfv = wfr[nt2], b2v = b2r[nt2];
                pl0 += wfv * __builtin_amdgcn_rcpf(1.f + __expf(-(acc2[nt2][0] + b2v)));
                pl1 += wfv * __builtin_amdgcn_rcpf(1.f + __expf(-(acc2[nt2][1] + b2v)));
                pl2 += wfv * __builtin_amdgcn_rcpf(1.f + __expf(-(acc2[nt2][2] + b2v)));
                pl3 += wfv * __builtin_amdgcn_rcpf(1.f + __expf(-(acc2[nt2][3] + b2v)));
            }
            ROR_ADD(pl0, 0x128); ROR_ADD(pl0, 0x124); ROR_ADD(pl0, 0x122); ROR_ADD(pl0, 0x121);
            ROR_ADD(pl1, 0x128); ROR_ADD(pl1, 0x124); ROR_ADD(pl1, 0x122); ROR_ADD(pl1, 0x121);
            ROR_ADD(pl2, 0x128); ROR_ADD(pl2, 0x124); ROR_ADD(pl2, 0x122); ROR_ADD(pl2, 0x121);
            ROR_ADD(pl3, 0x128); ROR_ADD(pl3, 0x124); ROR_ADD(pl3, 0x122); ROR_ADD(pl3, 0x121);
            const float myv = (c == 0) ? pl0 : (c == 1) ? pl1 : (c == 2) ? pl2 : pl3;
            if (c < 4) score[16 * t + 4 * g + c] = bf0 + myv;
        }
    }
    __syncthreads();

    // ---- block-wide masked softmax over L (R3 numerics: single global max/sum) ----
    const int flagv = flagG[0];
    float logit = -INFINITY;
    if (tid < L) {
        logit = score[tid];
        const size_t mi = (size_t)bb * L + tid;
        const int mv = flagv ? ((const int*)mask)[mi]
                             : (int)((const unsigned char*)mask)[mi];
        if (mv != 0) logit = -INFINITY;
    }
    float m = logit;
    #pragma unroll
    for (int off = 32; off > 0; off >>= 1)
        m = fmaxf(m, __shfl_xor(m, off));
    if (lane == 0) red_s[wv] = m;
    __syncthreads();
    const float gmax = fmaxf(fmaxf(red_s[0], red_s[1]), fmaxf(red_s[2], red_s[3]));

    const float e = __expf(logit - gmax);
    score[tid] = e;
    float ssum = e;
    #pragma unroll
    for (int off = 32; off > 0; off >>= 1)
        ssum += __shfl_xor(ssum, off);
    if (lane == 0) red_s[4 + wv] = ssum;
    __syncthreads();
    const float inv = 1.0f / (red_s[4] + red_s[5] + red_s[6] + red_s[7]);

    // ---- PV: wave wv covers rows 16*ll + 4*wv + g; lane sums e=[4c,4c+4) ----
    f32x4 oa = f32x4{0.f, 0.f, 0.f, 0.f};
    const float* vb = vmat + (size_t)bb * (L * E);
    #pragma unroll
    for (int ll = 0; ll < 13; ++ll) {
        const int row = 16 * ll + 4 * wv + g;
        if (row < L) {
            const float sv = score[row];
            const float4 v4 = *(const float4*)(vb + (size_t)row * E + c * 4);
            oa[0] += sv * v4.x; oa[1] += sv * v4.y;
            oa[2] += sv * v4.z; oa[3] += sv * v4.w;
        }
    }
    #pragma unroll
    for (int j = 0; j < 4; ++j) {
        oa[j] += __shfl_xor(oa[j], 16);
        oa[j] += __shfl_xor(oa[j], 32);
    }
    if (g == 0)
        *(float4*)&part_s[wv][4 * c] = make_float4(oa[0], oa[1], oa[2], oa[3]);
    __syncthreads();
    if (tid < 64) {
        const float o = (part_s[0][tid] + part_s[1][tid]
                       + part_s[2][tid] + part_s[3][tid]) * inv;
        out[(size_t)bb * E + tid] = o;
    }
}

} // namespace

extern "C" void kernel_launch(void* const* d_in, const int* in_sizes, int n_in,
                              void* d_out, int out_size, void* d_ws, size_t ws_size,
                              hipStream_t stream) {
    const float* q  = (const float*)d_in[0];
    const float* k  = (const float*)d_in[1];
    const float* v  = (const float*)d_in[2];
    const void*  mk = d_in[3];
    const float* W1 = (const float*)d_in[4];
    const float* b1 = (const float*)d_in[5];
    const float* W2 = (const float*)d_in[6];
    const float* b2 = (const float*)d_in[7];
    const float* Wf = (const float*)d_in[8];
    const float* bf = (const float*)d_in[9];
    float* out = (float*)d_out;

    const int B = in_sizes[0] / E;   // 4096

    char* ws = (char*)d_ws;
    float*          Af     = (float*)(ws + WS_AF);
    float*          Cf     = (float*)(ws + WS_CF);
    unsigned short* W2f    = (unsigned short*)(ws + WS_W2F);
    int*            flagG  = (int*)(ws + WS_FLAG);
    float*          cq_all = (float*)(ws + WS_CQ);

    const int prep_ids = 1216 + B * 20 + 1;
    k0_prep<<<(prep_ids + 255) / 256, 256, 0, stream>>>(W1, W2, q, b1, mk,
                                                        Af, Cf, W2f, cq_all, flagG, B);
    attn_main<<<B, 256, 0, stream>>>(q, k, v, mk, b2, Wf, bf,
                                     Af, Cf, W2f, cq_all, flagG, out);
}